// Round 5
// baseline (379.745 us; speedup 1.0000x reference)
//
#include <hip/hip_runtime.h>
#include <hip/hip_bf16.h>
#include <stdint.h>

#define B_DIM   8192
#define IN_DIM  4096
#define OUT_DIM 4096
#define BSZ     64
#define NBR_    64
#define BPR_    16
#define KTOT    1024
#define MT      128            // rows per block tile (was 256; A now fp32 in LDS)
#define BKK     32
#define NSTEP   (KTOT / BKK)   // 32

typedef __attribute__((ext_vector_type(4))) float  floatx4;
typedef __attribute__((ext_vector_type(8))) short  shortx8;  // 8 bf16
typedef __attribute__((ext_vector_type(4))) float  fragc;    // 4 fp32 acc

static __device__ __forceinline__ unsigned short f2bf(float f) {
  __bf16 b = (__bf16)f;  // RTNE hardware cvt
  return __builtin_bit_cast(unsigned short, b);
}

// 8 fp32 -> packed 8 bf16; compiler fuses pairs to v_cvt_pk_bf16_f32.
static __device__ __forceinline__ shortx8 pack8(floatx4 a, floatx4 b) {
  shortx8 p;
  p[0] = (short)f2bf(a[0]); p[1] = (short)f2bf(a[1]);
  p[2] = (short)f2bf(a[2]); p[3] = (short)f2bf(a[3]);
  p[4] = (short)f2bf(b[0]); p[5] = (short)f2bf(b[1]);
  p[6] = (short)f2bf(b[2]); p[7] = (short)f2bf(b[3]);
  return p;
}

__device__ __forceinline__ void gload_lds16(const void* g, void* l) {
  // 16B/lane, LDS dest = wave-uniform base + lane*16
  __builtin_amdgcn_global_load_lds(
      (const __attribute__((address_space(1))) unsigned int*)g,
      (__attribute__((address_space(3))) unsigned int*)l, 16, 0, 0);
}

// ---- cvt_v: fp32 -> bf16 for values only (body = cvt2's verified v-branch)
__global__ __launch_bounds__(256)
void cvt_v(const float* __restrict__ v, unsigned short* __restrict__ vb, int n8) {
  const int idx = blockIdx.x * 256 + threadIdx.x;
  if (idx >= n8) return;
  floatx4 a = ((const floatx4*)v)[2 * idx];
  floatx4 b = ((const floatx4*)v)[2 * idx + 1];
  uint4 o;
  o.x = (unsigned int)f2bf(a.x) | ((unsigned int)f2bf(a.y) << 16);
  o.y = (unsigned int)f2bf(a.z) | ((unsigned int)f2bf(a.w) << 16);
  o.z = (unsigned int)f2bf(b.x) | ((unsigned int)f2bf(b.y) << 16);
  o.w = (unsigned int)f2bf(b.z) | ((unsigned int)f2bf(b.w) << 16);
  ((uint4*)vb)[idx] = o;
}

// ---------------- block-sparse GEMM, fp32-A staging -----------------------
// Round-4 verified pipeline unchanged: 4 LDS buffers, 3-deep prefetch,
// steady-state vmcnt(10) (5 loads/wave/stage), one s_barrier per K-step,
// global_load_lds w=16, verified B path + epilogue.
// NEW: A staged as fp32 directly from x (no xb intermediate). MT=128 so
// A buffers are 4x16KB + B 4x4KB = 80KB -> 2 blocks/CU preserved.
// A swizzle (8 slots of 16B per 128B row): store global chunk g = s^(row&7)
// at slot s; read chunk c at slot c^(l16&7). Fragment content (k quad*8..+7
// of row l16) identical to the verified round-4 mapping; pack8 (RTNE) after
// ds_read gives numerics identical to the old cvt2+bf16 path.
// Decode: XCD (bid&7) owns m-tiles [xcd*8, xcd*8+8) x all 64 r, r fastest:
// 64 co-resident blocks/XCD sweep one m-tile (2MB fp32 slice, L2-resident);
// each m-tile HBM-fetched by exactly one XCD.
__global__ __launch_bounds__(256, 2)
void bsr_gemm(const float* __restrict__ x,
              const unsigned short* __restrict__ vb,
              const float* __restrict__ bias, const int* __restrict__ colidx,
              float* __restrict__ out) {
  const int bid  = blockIdx.x;
  const int xcd  = bid & 7;
  const int slot = bid >> 3;            // 0..511 per XCD, r fastest
  const int r    = slot & 63;           // block-row 0..63
  const int mt   = xcd * 8 + (slot >> 6);  // m-tile 0..63, 8 per XCD
  const int m0   = mt * MT;

  const int tid  = threadIdx.x;
  const int wave = tid >> 6;
  const int lane = tid & 63;
  const int l16  = lane & 15;
  const int quad = lane >> 4;
  // B staging (verified round-4 pattern, unchanged)
  const int sub  = lane >> 2;            // row within 16-row B chunk
  const int slt  = lane & 3;             // 16B slot within 64B B row
  const int gsw  = slt ^ ((sub >> 1) & 3);
  const int csw  = quad ^ ((l16 >> 1) & 3);
  // A staging (fp32, 128B rows = 8 slots)
  const int sub8 = lane >> 3;            // row within 8-row A chunk
  const int slt8 = lane & 7;             // 16B slot within 128B A row
  const int gsw8 = slt8 ^ sub8;          // global chunk this lane stages
  const int s0   = (2 * quad) ^ (l16 & 7);  // LDS slot of chunk 2*quad

  __shared__ __align__(16) float          As0[MT * BKK];
  __shared__ __align__(16) float          As1[MT * BKK];
  __shared__ __align__(16) float          As2[MT * BKK];
  __shared__ __align__(16) float          As3[MT * BKK];
  __shared__ __align__(16) unsigned short Bs0[BSZ * BKK];
  __shared__ __align__(16) unsigned short Bs1[BSZ * BKK];
  __shared__ __align__(16) unsigned short Bs2[BSZ * BKK];
  __shared__ __align__(16) unsigned short Bs3[BSZ * BKK];

  int cidx[BPR_];
  #pragma unroll
  for (int j = 0; j < BPR_; ++j)
    cidx[j] = __builtin_amdgcn_readfirstlane(colidx[r * BPR_ + j]);

  // per-lane staging source bases
  const float* gA =
      x + (size_t)(m0 + wave * 32 + sub8) * IN_DIM + gsw8 * 4;
  const unsigned short* gB =
      vb + ((size_t)(r * BPR_) * BSZ + wave * 16 + sub) * BSZ + gsw * 8;

  // B LDS read offset (shorts)
  const int boff = l16 * BKK + csw * 8;

  fragc acc[2][4] = {};

#define STAGE(k, As, Bs)                                                      \
  {                                                                           \
    const int jb_ = (k) >> 1, kb0_ = ((k) & 1) * BKK;                         \
    const int colo_ = cidx[jb_] * BSZ + kb0_;                                 \
    _Pragma("unroll")                                                         \
    for (int i_ = 0; i_ < 4; ++i_)                                            \
      gload_lds16(gA + (size_t)i_ * 8 * IN_DIM + colo_,                       \
                  &As[(wave * 32 + i_ * 8) * BKK]);                           \
    gload_lds16(gB + (size_t)jb_ * BSZ * BSZ + kb0_,                          \
                &Bs[(wave * 16) * BKK]);                                      \
  }

#define COMP(As, Bs)                                                          \
  {                                                                           \
    shortx8 af_[2], bf_[4];                                                   \
    _Pragma("unroll")                                                         \
    for (int mi = 0; mi < 2; ++mi) {                                          \
      const float* ap_ = &As[(wave * 32 + mi * 16 + l16) * BKK];              \
      floatx4 a0_ = *(const floatx4*)(ap_ + s0 * 4);                          \
      floatx4 a1_ = *(const floatx4*)(ap_ + (s0 ^ 1) * 4);                    \
      af_[mi] = pack8(a0_, a1_);                                              \
    }                                                                         \
    _Pragma("unroll")                                                         \
    for (int ni = 0; ni < 4; ++ni)                                            \
      bf_[ni] = *(const shortx8*)&Bs[boff + ni * 16 * BKK];                   \
    _Pragma("unroll")                                                         \
    for (int mi = 0; mi < 2; ++mi) {                                          \
      _Pragma("unroll")                                                       \
      for (int ni = 0; ni < 4; ++ni)                                          \
        acc[mi][ni] = __builtin_amdgcn_mfma_f32_16x16x32_bf16(                \
            af_[mi], bf_[ni], acc[mi][ni], 0, 0, 0);                          \
    }                                                                         \
  }

  // steady state: stages k, k+1, k+2 in flight (15 loads). Wait for the
  // oldest 5 (stage k) -> vmcnt(10); tail 10 -> 5 -> 0. k is compile-time
  // constant after full unroll, so the branches fold away.
#define ITER(k, Ac, Bc, An, Bn)                                              \
  do {                                                                       \
    if ((k) < NSTEP - 2)                                                     \
      asm volatile("s_waitcnt vmcnt(10)" ::: "memory");                      \
    else if ((k) == NSTEP - 2)                                               \
      asm volatile("s_waitcnt vmcnt(5)" ::: "memory");                       \
    else                                                                     \
      asm volatile("s_waitcnt vmcnt(0)" ::: "memory");                       \
    __builtin_amdgcn_s_barrier();                                            \
    asm volatile("" ::: "memory");                                           \
    if ((k) + 3 < NSTEP) { STAGE((k) + 3, An, Bn); }                         \
    COMP(Ac, Bc);                                                            \
  } while (0)

  STAGE(0, As0, Bs0);
  STAGE(1, As1, Bs1);
  STAGE(2, As2, Bs2);

  #pragma unroll
  for (int k = 0; k < NSTEP; k += 4) {
    ITER(k + 0, As0, Bs0, As3, Bs3);
    ITER(k + 1, As1, Bs1, As0, Bs0);
    ITER(k + 2, As2, Bs2, As1, Bs1);
    ITER(k + 3, As3, Bs3, As2, Bs2);
  }
#undef STAGE
#undef COMP
#undef ITER

  // epilogue: C/D layout col=lane&15, row=quad*4+reg (verified)
  #pragma unroll
  for (int ni = 0; ni < 4; ++ni) {
    const int col = r * BSZ + ni * 16 + l16;
    const float bv = bias[col];
    #pragma unroll
    for (int mi = 0; mi < 2; ++mi) {
      #pragma unroll
      for (int reg = 0; reg < 4; ++reg) {
        const int row = m0 + wave * 32 + mi * 16 + quad * 4 + reg;
        out[(size_t)row * OUT_DIM + col] = acc[mi][ni][reg] + bv;
      }
    }
  }
}

// ---------------- correctness-only fallback (no workspace) -----------------
__global__ __launch_bounds__(256)
void bsr_naive(const float* __restrict__ x, const float* __restrict__ v,
               const float* __restrict__ bias, const int* __restrict__ colidx,
               float* __restrict__ out) {
  const size_t gid = (size_t)blockIdx.x * blockDim.x + threadIdx.x;
  if (gid >= (size_t)B_DIM * OUT_DIM) return;
  const int b = gid / OUT_DIM;
  const int oc = gid % OUT_DIM;
  const int rr = oc / BSZ, o = oc % BSZ;
  float s = bias[oc];
  for (int j = 0; j < BPR_; ++j) {
    const int c = colidx[rr * BPR_ + j];
    const float* xp = x + (size_t)b * IN_DIM + c * BSZ;
    const float* vp = v + ((size_t)(rr * BPR_ + j) * BSZ + o) * BSZ;
    for (int k = 0; k < BSZ; ++k) s += vp[k] * xp[k];
  }
  out[gid] = s;
}

extern "C" void kernel_launch(void* const* d_in, const int* in_sizes, int n_in,
                              void* d_out, int out_size, void* d_ws, size_t ws_size,
                              hipStream_t stream) {
  const float* x    = (const float*)d_in[0];
  const float* vals = (const float*)d_in[1];
  const float* bias = (const float*)d_in[2];
  const int*   cols = (const int*)d_in[3];
  float* out = (float*)d_out;

  const size_t v_elems  = (size_t)NBR_ * BPR_ * BSZ * BSZ;   // 4.19M
  const size_t vb_bytes = v_elems * sizeof(unsigned short);  // 8.4 MB

  if (ws_size >= vb_bytes) {
    unsigned short* vbp = (unsigned short*)d_ws;
    const int n8 = (int)(v_elems / 8);                       // 524288
    cvt_v<<<dim3((unsigned)((n8 + 255) / 256)), dim3(256), 0, stream>>>(
        vals, vbp, n8);
    bsr_gemm<<<dim3(NBR_ * (B_DIM / MT)), dim3(256), 0, stream>>>(
        x, vbp, bias, cols, out);
  } else {
    const size_t n = (size_t)B_DIM * OUT_DIM;
    bsr_naive<<<dim3((unsigned)((n + 255) / 256)), dim3(256), 0, stream>>>(
        x, vals, bias, cols, out);
  }
}